// Round 7
// baseline (1034.636 us; speedup 1.0000x reference)
//
#include <hip/hip_runtime.h>

typedef float f4 __attribute__((ext_vector_type(4)));
typedef float f2 __attribute__((ext_vector_type(2)));

#define NB    1024
#define TT    256
#define EE    100
#define VOCAB 5000
#define GG1   256   // 4*H1
#define GG2   128   // 4*H2
#define RPB   2
#define NTHR  512

__device__ __forceinline__ float fast_sigmoid(float x) {
  return __builtin_amdgcn_rcpf(1.0f + __expf(-x));
}

// quad_perm DPP cross-lane (VALU pipe, no LDS): 0xB1 = xor1, 0x4E = xor2
template <int CTRL>
__device__ __forceinline__ float dppq(float x) {
  return __int_as_float(
      __builtin_amdgcn_mov_dpp(__float_as_int(x), CTRL, 0xF, 0xF, true));
}
__device__ __forceinline__ float swz_xor4(float x) {  // lane ^= 4 (LDS pipe)
  return __int_as_float(__builtin_amdgcn_ds_swizzle(__float_as_int(x), 0x101F));
}

// Reduce 4 gate-accumulators across a quad; lane sg (=lane&3) returns gate sg's sum.
__device__ __forceinline__ float qredsel(float ai, float af, float ag, float ao, int sg) {
  ai += dppq<0xB1>(ai); af += dppq<0xB1>(af);
  ag += dppq<0xB1>(ag); ao += dppq<0xB1>(ao);
  float pl = (sg & 1) ? af : ai;
  float ph = (sg & 1) ? ao : ag;
  pl += dppq<0x4E>(pl); ph += dppq<0x4E>(ph);
  return (sg & 2) ? ph : pl;
}

// Quad-cooperative activation + state update. z = pre-activation for gate sg.
// c authoritative on lane sg==1; h carried in-register on lane sg==3.
__device__ __forceinline__ void gate_up(float z, int sg, bool m, float& c, float& h) {
  const bool th = (sg == 2);
  float e = __expf(th ? 2.0f * z : -z);
  float r = __builtin_amdgcn_rcpf(1.0f + e);
  float v = th ? (1.0f - 2.0f * r) : r;            // lanes: i, f, g, o
  float ig = v * dppq<0x4E>(v);                    // lane0: i*g
  float fc = v * c;                                // lane1: f*c
  float cn = fc + dppq<0xB1>(ig);                  // lane1: c_new
  float cu = m ? cn : c;
  c = cu;
  float e2 = __expf(2.0f * cu);
  float tc = 1.0f - 2.0f * __builtin_amdgcn_rcpf(1.0f + e2);  // lane1: tanh(c)
  float hn = v * dppq<0x4E>(tc);                   // lane3: o*tanh(c)
  if (m) h = hn;
}

// ---- K1: emb_zi[v][u*4+g] = b1[g*64+u] + sum_k emb[v][k]*W1[k][g*64+u] ----
__global__ __launch_bounds__(256) void emb_gemm(
    const float* __restrict__ emb, const float* __restrict__ W1,
    const float* __restrict__ b1, float* __restrict__ emb_zi)
{
  __shared__ float sE[8][EE];
  const int j  = threadIdx.x;           // column g*64+u
  const int v0 = blockIdx.x * 8;
  for (int idx = j; idx < 8 * EE; idx += 256) {
    int r = idx / EE, k = idx % EE;
    sE[r][k] = emb[(size_t)(v0 + r) * EE + k];
  }
  __syncthreads();
  float acc[8];
  const float bb = b1[j];
  #pragma unroll
  for (int r = 0; r < 8; ++r) acc[r] = bb;
  for (int k = 0; k < EE; ++k) {
    float w = W1[k * GG1 + j];
    #pragma unroll
    for (int r = 0; r < 8; ++r) acc[r] = fmaf(sE[r][k], w, acc[r]);
  }
  const int slot = (j & 63) * 4 + (j >> 6);   // u*4 + g
  #pragma unroll
  for (int r = 0; r < 8; ++r) emb_zi[(size_t)(v0 + r) * GG1 + slot] = acc[r];
}

// ---- K2: persistent 2-layer LSTM; wave-specialized; 1 barrier/step ----
// Row-interleaved unified h-buffer sHC[parity][96][2]: cols 0..63 = h1,
// 64..95 = h2; [col][r] pairs so ds_read_b128 yields 2 cols x 2 rows and
// the row-pair FMAs pack into v_pk_fma_f32.
// Step i: writes -> parity i&1; reads <- parity (i&1)^1.
__global__ __launch_bounds__(NTHR) __attribute__((amdgpu_waves_per_eu(4, 4)))
void lstm_fused(
    const int* __restrict__ tokens, const float* __restrict__ emb_zi,
    const float* __restrict__ U1,
    const float* __restrict__ W2, const float* __restrict__ U2, const float* __restrict__ b2,
    const float* __restrict__ Wd, const float* __restrict__ bd,
    float* __restrict__ out)
{
  __shared__ __align__(16) float sHC[2][96][2];
  __shared__ int2 sTokP[TT];

  const int tid  = threadIdx.x;
  const int row0 = blockIdx.x * RPB;
  const bool L2g = (tid >= 256);
  const int  lt  = tid & 255;
  const int  u   = lt >> 2;            // L1 unit (0..63)
  const int  sg  = lt & 3;             // gate id within quad
  const int  u2  = lt >> 3;            // L2 unit (0..31)
  const int  s2  = lt & 7;             // L2 k-eighth

  // ---- weights into registers ----
  f4 wU[16];
  float biasg = 0.0f;
  if (!L2g) {
    #pragma unroll
    for (int kk = 0; kk < 16; ++kk) {
      int k = 16 * sg + kk;            // quad lane sg owns k-quarter sg
      f4 w;
      w[0] = U1[k * GG1 + u];
      w[1] = U1[k * GG1 + 64 + u];
      w[2] = U1[k * GG1 + 128 + u];
      w[3] = U1[k * GG1 + 192 + u];
      wU[kk] = w;
    }
    asm volatile("" : "+v"(wU[0]), "+v"(wU[1]), "+v"(wU[2]), "+v"(wU[3]),
                      "+v"(wU[4]), "+v"(wU[5]), "+v"(wU[6]), "+v"(wU[7]),
                      "+v"(wU[8]), "+v"(wU[9]), "+v"(wU[10]), "+v"(wU[11]),
                      "+v"(wU[12]), "+v"(wU[13]), "+v"(wU[14]), "+v"(wU[15]));
  } else {
    #pragma unroll
    for (int kk = 0; kk < 12; ++kk) {
      int k = 12 * s2 + kk;            // 0..63 -> W2 row k; 64..95 -> U2 row k-64
      const float* src = (k < 64) ? &W2[(size_t)k * GG2] : &U2[(size_t)(k - 64) * GG2];
      f4 w;
      w[0] = src[u2]; w[1] = src[32 + u2]; w[2] = src[64 + u2]; w[3] = src[96 + u2];
      wU[kk] = w;
    }
    asm volatile("" : "+v"(wU[0]), "+v"(wU[1]), "+v"(wU[2]), "+v"(wU[3]),
                      "+v"(wU[4]), "+v"(wU[5]), "+v"(wU[6]), "+v"(wU[7]),
                      "+v"(wU[8]), "+v"(wU[9]), "+v"(wU[10]), "+v"(wU[11]));
    biasg = b2[sg * 32 + u2];
  }

  // ---- one-time LDS init ----
  if (tid < TT)
    sTokP[tid] = make_int2(tokens[(size_t)row0 * TT + tid],
                           tokens[(size_t)(row0 + 1) * TT + tid]);
  if (tid < 2 * 96 * 2) ((float*)sHC)[tid] = 0.0f;
  float c0 = 0.0f, c1 = 0.0f;          // cell state per row (lane sg==1)
  float h0r = 0.0f, h1r = 0.0f;        // hidden per row (writer lane)
  __syncthreads();

  // ---- prologue (L1 lanes): token pair + z_x for t=0 ----
  int2  tokc = make_int2(0, 0);
  float zxc0 = 0.f, zxc1 = 0.f;
  if (!L2g) {
    tokc = sTokP[0];
    zxc0 = emb_zi[(size_t)tokc.x * GG1 + lt];
    zxc1 = emb_zi[(size_t)tokc.y * GG1 + lt];
  }

  for (int i = 0; i <= TT; ++i) {
    const int rbuf = (i & 1) ^ 1, wbuf = i & 1;
    if (!L2g) {
      if (i < TT) {                                 // L1 step t = i
        const bool m0 = (tokc.x != 0), m1 = (tokc.y != 0);
        int2 tokn = make_int2(0, 0);
        float zxn0 = 0.f, zxn1 = 0.f;
        if (i + 1 < TT) {                           // prefetch z_x(t+1)
          tokn = sTokP[i + 1];
          zxn0 = emb_zi[(size_t)tokn.x * GG1 + lt];
          zxn1 = emb_zi[(size_t)tokn.y * GG1 + lt];
        }
        const f4* hp = (const f4*)&sHC[rbuf][16 * sg][0];  // 2 cols x 2 rows per f4
        f2 acc[4] = {{0.f, 0.f}, {0.f, 0.f}, {0.f, 0.f}, {0.f, 0.f}};
        #pragma unroll
        for (int q = 0; q < 8; ++q) {               // cols 16sg+2q, 16sg+2q+1
          f4 hv = hp[q];
          f2 hlo = {hv[0], hv[1]};                  // col 2q : {row0, row1}
          f2 hhi = {hv[2], hv[3]};                  // col 2q+1
          f4 wl = wU[2 * q], wh = wU[2 * q + 1];
          #pragma unroll
          for (int g = 0; g < 4; ++g) {
            f2 wsl = {wl[g], wl[g]};
            f2 wsh = {wh[g], wh[g]};
            acc[g] = __builtin_elementwise_fma(hlo, wsl, acc[g]);
            acc[g] = __builtin_elementwise_fma(hhi, wsh, acc[g]);
          }
        }
        float z0 = qredsel(acc[0][0], acc[1][0], acc[2][0], acc[3][0], sg) + zxc0;
        float z1 = qredsel(acc[0][1], acc[1][1], acc[2][1], acc[3][1], sg) + zxc1;
        gate_up(z0, sg, m0, c0, h0r);
        gate_up(z1, sg, m1, c1, h1r);
        if (sg == 3) {
          f2 hw; hw[0] = h0r; hw[1] = h1r;
          *(f2*)&sHC[wbuf][u][0] = hw;
        }
        tokc = tokn; zxc0 = zxn0; zxc1 = zxn1;
      }
    } else {
      if (i >= 1) {                                 // L2 step tt = i-1
        const int tt = i - 1;
        int2 tk = sTokP[tt];
        const bool m0 = (tk.x != 0), m1 = (tk.y != 0);
        const f4* hp = (const f4*)&sHC[rbuf][12 * s2][0];
        f2 acc[4] = {{0.f, 0.f}, {0.f, 0.f}, {0.f, 0.f}, {0.f, 0.f}};
        #pragma unroll
        for (int q = 0; q < 6; ++q) {               // cols 12s2+2q, +2q+1
          f4 hv = hp[q];
          f2 hlo = {hv[0], hv[1]};
          f2 hhi = {hv[2], hv[3]};
          f4 wl = wU[2 * q], wh = wU[2 * q + 1];
          #pragma unroll
          for (int g = 0; g < 4; ++g) {
            f2 wsl = {wl[g], wl[g]};
            f2 wsh = {wh[g], wh[g]};
            acc[g] = __builtin_elementwise_fma(hlo, wsl, acc[g]);
            acc[g] = __builtin_elementwise_fma(hhi, wsh, acc[g]);
          }
        }
        float q0 = qredsel(acc[0][0], acc[1][0], acc[2][0], acc[3][0], sg);
        float q1 = qredsel(acc[0][1], acc[1][1], acc[2][1], acc[3][1], sg);
        float z0 = q0 + swz_xor4(q0) + biasg;       // full 8-lane k-sum
        float z1 = q1 + swz_xor4(q1) + biasg;
        gate_up(z0, sg, m0, c0, h0r);
        gate_up(z1, sg, m1, c1, h1r);
        if (s2 == 3) {
          f2 hw; hw[0] = h0r; hw[1] = h1r;
          *(f2*)&sHC[wbuf][64 + u2][0] = hw;
        }
      }
    }
    __syncthreads();
  }

  // ---- epilogue: out = sigmoid(h2 @ Wd + bd); final h2 in parity 0 ----
  if (tid < RPB * 4) {
    int r = tid >> 2, o = tid & 3;
    float a = bd[o];
    #pragma unroll
    for (int kk = 0; kk < 32; ++kk)
      a = fmaf(sHC[0][64 + kk][r], Wd[kk * 4 + o], a);
    out[(size_t)(row0 + r) * 4 + o] = fast_sigmoid(a);
  }
}

extern "C" void kernel_launch(void* const* d_in, const int* in_sizes, int n_in,
                              void* d_out, int out_size, void* d_ws, size_t ws_size,
                              hipStream_t stream) {
  const int*   tokens = (const int*)d_in[0];
  const float* emb    = (const float*)d_in[1];
  const float* W1     = (const float*)d_in[2];
  const float* U1     = (const float*)d_in[3];
  const float* b1     = (const float*)d_in[4];
  const float* W2     = (const float*)d_in[5];
  const float* U2     = (const float*)d_in[6];
  const float* b2     = (const float*)d_in[7];
  const float* Wd     = (const float*)d_in[8];
  const float* bd     = (const float*)d_in[9];
  float* out    = (float*)d_out;
  float* emb_zi = (float*)d_ws;         // 5000*256*4 = 5.12 MB scratch

  emb_gemm<<<dim3(VOCAB / 8), dim3(256), 0, stream>>>(emb, W1, b1, emb_zi);
  lstm_fused<<<dim3(NB / RPB), dim3(NTHR), 0, stream>>>(
      tokens, emb_zi, U1, W2, U2, b2, Wd, bd, out);
}

// Round 8
// 368.687 us; speedup vs baseline: 2.8063x; 2.8063x over previous
//
#include <hip/hip_runtime.h>

typedef float f4 __attribute__((ext_vector_type(4)));

#define NB    1024
#define TT    256
#define EE    100
#define VOCAB 5000
#define GG1   256   // 4*H1
#define GG2   128   // 4*H2
#define RPB   4
#define NTHR  512

__device__ __forceinline__ float fast_sigmoid(float x) {
  return __builtin_amdgcn_rcpf(1.0f + __expf(-x));
}

// quad_perm DPP cross-lane (VALU pipe, no LDS): 0xB1 = xor1, 0x4E = xor2
template <int CTRL>
__device__ __forceinline__ float dppq(float x) {
  return __int_as_float(
      __builtin_amdgcn_mov_dpp(__float_as_int(x), CTRL, 0xF, 0xF, true));
}
__device__ __forceinline__ float swz_xor4(float x) {  // lane ^= 4 (LDS pipe)
  return __int_as_float(__builtin_amdgcn_ds_swizzle(__float_as_int(x), 0x101F));
}

// Reduce 4 gate-accumulators across a quad; lane sg (=lane&3) returns gate sg's sum.
__device__ __forceinline__ float qredsel(float ai, float af, float ag, float ao, int sg) {
  ai += dppq<0xB1>(ai); af += dppq<0xB1>(af);
  ag += dppq<0xB1>(ag); ao += dppq<0xB1>(ao);
  float pl = (sg & 1) ? af : ai;
  float ph = (sg & 1) ? ao : ag;
  pl += dppq<0x4E>(pl); ph += dppq<0x4E>(ph);
  return (sg & 2) ? ph : pl;
}

// Quad-cooperative activation + state update. z = pre-activation for gate sg.
// c authoritative on lane sg==1; h carried in-register on lane sg==3.
__device__ __forceinline__ void gate_up(float z, int sg, bool m, float& c, float& h) {
  const bool th = (sg == 2);
  float e = __expf(th ? 2.0f * z : -z);
  float r = __builtin_amdgcn_rcpf(1.0f + e);
  float v = th ? (1.0f - 2.0f * r) : r;            // lanes: i, f, g, o
  float ig = v * dppq<0x4E>(v);                    // lane0: i*g
  float fc = v * c;                                // lane1: f*c
  float cn = fc + dppq<0xB1>(ig);                  // lane1: c_new
  float cu = m ? cn : c;
  c = cu;
  float e2 = __expf(2.0f * cu);
  float tc = 1.0f - 2.0f * __builtin_amdgcn_rcpf(1.0f + e2);  // lane1: tanh(c)
  float hn = v * dppq<0x4E>(tc);                   // lane3: o*tanh(c)
  if (m) h = hn;
}

// ---- K1: emb_zi[v][u*4+g] = b1[g*64+u] + sum_k emb[v][k]*W1[k][g*64+u] ----
__global__ __launch_bounds__(256) void emb_gemm(
    const float* __restrict__ emb, const float* __restrict__ W1,
    const float* __restrict__ b1, float* __restrict__ emb_zi)
{
  __shared__ float sE[8][EE];
  const int j  = threadIdx.x;           // column g*64+u
  const int v0 = blockIdx.x * 8;
  for (int idx = j; idx < 8 * EE; idx += 256) {
    int r = idx / EE, k = idx % EE;
    sE[r][k] = emb[(size_t)(v0 + r) * EE + k];
  }
  __syncthreads();
  float acc[8];
  const float bb = b1[j];
  #pragma unroll
  for (int r = 0; r < 8; ++r) acc[r] = bb;
  for (int k = 0; k < EE; ++k) {
    float w = W1[k * GG1 + j];
    #pragma unroll
    for (int r = 0; r < 8; ++r) acc[r] = fmaf(sE[r][k], w, acc[r]);
  }
  const int slot = (j & 63) * 4 + (j >> 6);   // u*4 + g
  #pragma unroll
  for (int r = 0; r < 8; ++r) emb_zi[(size_t)(v0 + r) * GG1 + slot] = acc[r];
}

// ---- K2: persistent 2-layer LSTM; wave-specialized; 1 barrier/step; RPB=4 ----
// h-buffer sHC[parity][row][96]: floats 0..63 = h1, 64..95 = h2.
// Step i: writes -> parity i&1 (L1: h1(i), L2: h2(i-1));
//         reads  <- parity (i&1)^1 (h1(i-1), h2(i-2)).
// 1 block/CU, 2 waves/SIMD, waves_per_eu(2,2) -> 256-VGPR budget so the
// 64 (L1) / 48 (L2) weight floats live in architectural VGPRs.
__global__ __launch_bounds__(NTHR) __attribute__((amdgpu_waves_per_eu(2, 2)))
void lstm_fused(
    const int* __restrict__ tokens, const float* __restrict__ emb_zi,
    const float* __restrict__ U1,
    const float* __restrict__ W2, const float* __restrict__ U2, const float* __restrict__ b2,
    const float* __restrict__ Wd, const float* __restrict__ bd,
    float* __restrict__ out)
{
  __shared__ __align__(16) float sHC[2][RPB][96];
  __shared__ int4 sTokP[TT];

  const int tid  = threadIdx.x;
  const int row0 = blockIdx.x * RPB;
  const bool L2g = (tid >= 256);
  const int  lt  = tid & 255;
  const int  u   = lt >> 2;            // L1 unit (0..63)
  const int  sg  = lt & 3;             // gate id within quad
  const int  u2  = lt >> 3;            // L2 unit (0..31)
  const int  s2  = lt & 7;             // L2 k-eighth

  // ---- weights into registers ----
  f4 wU[16];
  float biasg = 0.0f;
  if (!L2g) {
    #pragma unroll
    for (int kk = 0; kk < 16; ++kk) {
      int k = 16 * sg + kk;            // quad lane sg owns k-quarter sg
      f4 w;
      w[0] = U1[k * GG1 + u];
      w[1] = U1[k * GG1 + 64 + u];
      w[2] = U1[k * GG1 + 128 + u];
      w[3] = U1[k * GG1 + 192 + u];
      wU[kk] = w;
    }
  } else {
    #pragma unroll
    for (int kk = 0; kk < 12; ++kk) {
      int k = 12 * s2 + kk;            // 0..63 -> W2 row k; 64..95 -> U2 row k-64
      const float* src = (k < 64) ? &W2[(size_t)k * GG2] : &U2[(size_t)(k - 64) * GG2];
      f4 w;
      w[0] = src[u2]; w[1] = src[32 + u2]; w[2] = src[64 + u2]; w[3] = src[96 + u2];
      wU[kk] = w;
    }
    biasg = b2[sg * 32 + u2];
  }

  // ---- one-time LDS init ----
  if (tid < TT) {
    int4 tp;
    tp.x = tokens[(size_t)(row0 + 0) * TT + tid];
    tp.y = tokens[(size_t)(row0 + 1) * TT + tid];
    tp.z = tokens[(size_t)(row0 + 2) * TT + tid];
    tp.w = tokens[(size_t)(row0 + 3) * TT + tid];
    sTokP[tid] = tp;
  }
  #pragma unroll
  for (int it = 0; it < 2; ++it) {
    int idx = tid + it * NTHR;
    if (idx < 2 * RPB * 96) ((float*)sHC)[idx] = 0.0f;
  }
  float c0 = 0.f, c1 = 0.f, c2 = 0.f, c3 = 0.f;    // cell (lane sg==1)
  float h0r = 0.f, h1r = 0.f, h2r = 0.f, h3r = 0.f; // hidden (writer lane)
  __syncthreads();

  // ---- prologue (L1 lanes): tokens + z_x for t=0 ----
  int4  tokc = make_int4(0, 0, 0, 0);
  float zx0 = 0.f, zx1 = 0.f, zx2 = 0.f, zx3 = 0.f;
  if (!L2g) {
    tokc = sTokP[0];
    zx0 = emb_zi[(size_t)tokc.x * GG1 + lt];
    zx1 = emb_zi[(size_t)tokc.y * GG1 + lt];
    zx2 = emb_zi[(size_t)tokc.z * GG1 + lt];
    zx3 = emb_zi[(size_t)tokc.w * GG1 + lt];
  }

  for (int i = 0; i <= TT; ++i) {
    const int rbuf = (i & 1) ^ 1, wbuf = i & 1;
    if (!L2g) {
      if (i < TT) {                                 // L1 step t = i
        const bool m0 = (tokc.x != 0), m1 = (tokc.y != 0);
        const bool m2 = (tokc.z != 0), m3 = (tokc.w != 0);
        int4 tokn = make_int4(0, 0, 0, 0);
        float zn0 = 0.f, zn1 = 0.f, zn2 = 0.f, zn3 = 0.f;
        if (i + 1 < TT) {                           // prefetch z_x(t+1)
          tokn = sTokP[i + 1];
          zn0 = emb_zi[(size_t)tokn.x * GG1 + lt];
          zn1 = emb_zi[(size_t)tokn.y * GG1 + lt];
          zn2 = emb_zi[(size_t)tokn.z * GG1 + lt];
          zn3 = emb_zi[(size_t)tokn.w * GG1 + lt];
        }
        float ai[RPB] = {0.f, 0.f, 0.f, 0.f}, af[RPB] = {0.f, 0.f, 0.f, 0.f};
        float ag[RPB] = {0.f, 0.f, 0.f, 0.f}, ao[RPB] = {0.f, 0.f, 0.f, 0.f};
        #pragma unroll
        for (int q = 0; q < 4; ++q) {
          f4 hv[RPB];
          #pragma unroll
          for (int r = 0; r < RPB; ++r)
            hv[r] = *(const f4*)&sHC[rbuf][r][16 * sg + 4 * q];
          #pragma unroll
          for (int kk = 0; kk < 4; ++kk) {
            f4 w = wU[4 * q + kk];
            #pragma unroll
            for (int r = 0; r < RPB; ++r) {
              ai[r] = fmaf(hv[r][kk], w[0], ai[r]);
              af[r] = fmaf(hv[r][kk], w[1], af[r]);
              ag[r] = fmaf(hv[r][kk], w[2], ag[r]);
              ao[r] = fmaf(hv[r][kk], w[3], ao[r]);
            }
          }
        }
        float z0 = qredsel(ai[0], af[0], ag[0], ao[0], sg) + zx0;
        float z1 = qredsel(ai[1], af[1], ag[1], ao[1], sg) + zx1;
        float z2 = qredsel(ai[2], af[2], ag[2], ao[2], sg) + zx2;
        float z3 = qredsel(ai[3], af[3], ag[3], ao[3], sg) + zx3;
        gate_up(z0, sg, m0, c0, h0r);
        gate_up(z1, sg, m1, c1, h1r);
        gate_up(z2, sg, m2, c2, h2r);
        gate_up(z3, sg, m3, c3, h3r);
        if (sg == 3) {
          sHC[wbuf][0][u] = h0r; sHC[wbuf][1][u] = h1r;
          sHC[wbuf][2][u] = h2r; sHC[wbuf][3][u] = h3r;
        }
        tokc = tokn; zx0 = zn0; zx1 = zn1; zx2 = zn2; zx3 = zn3;
      }
    } else {
      if (i >= 1) {                                 // L2 step tt = i-1
        const int tt = i - 1;
        int4 tk = sTokP[tt];
        const bool m0 = (tk.x != 0), m1 = (tk.y != 0);
        const bool m2 = (tk.z != 0), m3 = (tk.w != 0);
        float ai[RPB] = {0.f, 0.f, 0.f, 0.f}, af[RPB] = {0.f, 0.f, 0.f, 0.f};
        float ag[RPB] = {0.f, 0.f, 0.f, 0.f}, ao[RPB] = {0.f, 0.f, 0.f, 0.f};
        #pragma unroll
        for (int q = 0; q < 3; ++q) {
          f4 hv[RPB];
          #pragma unroll
          for (int r = 0; r < RPB; ++r)
            hv[r] = *(const f4*)&sHC[rbuf][r][12 * s2 + 4 * q];
          #pragma unroll
          for (int kk = 0; kk < 4; ++kk) {
            f4 w = wU[4 * q + kk];
            #pragma unroll
            for (int r = 0; r < RPB; ++r) {
              ai[r] = fmaf(hv[r][kk], w[0], ai[r]);
              af[r] = fmaf(hv[r][kk], w[1], af[r]);
              ag[r] = fmaf(hv[r][kk], w[2], ag[r]);
              ao[r] = fmaf(hv[r][kk], w[3], ao[r]);
            }
          }
        }
        float q0 = qredsel(ai[0], af[0], ag[0], ao[0], sg);
        float q1 = qredsel(ai[1], af[1], ag[1], ao[1], sg);
        float q2 = qredsel(ai[2], af[2], ag[2], ao[2], sg);
        float q3 = qredsel(ai[3], af[3], ag[3], ao[3], sg);
        float z0 = q0 + swz_xor4(q0) + biasg;       // full 8-lane k-sum
        float z1 = q1 + swz_xor4(q1) + biasg;
        float z2 = q2 + swz_xor4(q2) + biasg;
        float z3 = q3 + swz_xor4(q3) + biasg;
        gate_up(z0, sg, m0, c0, h0r);
        gate_up(z1, sg, m1, c1, h1r);
        gate_up(z2, sg, m2, c2, h2r);
        gate_up(z3, sg, m3, c3, h3r);
        if (s2 == 3) {
          sHC[wbuf][0][64 + u2] = h0r; sHC[wbuf][1][64 + u2] = h1r;
          sHC[wbuf][2][64 + u2] = h2r; sHC[wbuf][3][64 + u2] = h3r;
        }
      }
    }
    __syncthreads();
  }

  // ---- epilogue: out = sigmoid(h2 @ Wd + bd); final h2 in parity TT&1 = 0 ----
  if (tid < RPB * 4) {
    int r = tid >> 2, o = tid & 3;
    float a = bd[o];
    #pragma unroll
    for (int kk = 0; kk < 32; ++kk)
      a = fmaf(sHC[0][r][64 + kk], Wd[kk * 4 + o], a);
    out[(size_t)(row0 + r) * 4 + o] = fast_sigmoid(a);
  }
}

extern "C" void kernel_launch(void* const* d_in, const int* in_sizes, int n_in,
                              void* d_out, int out_size, void* d_ws, size_t ws_size,
                              hipStream_t stream) {
  const int*   tokens = (const int*)d_in[0];
  const float* emb    = (const float*)d_in[1];
  const float* W1     = (const float*)d_in[2];
  const float* U1     = (const float*)d_in[3];
  const float* b1     = (const float*)d_in[4];
  const float* W2     = (const float*)d_in[5];
  const float* U2     = (const float*)d_in[6];
  const float* b2     = (const float*)d_in[7];
  const float* Wd     = (const float*)d_in[8];
  const float* bd     = (const float*)d_in[9];
  float* out    = (float*)d_out;
  float* emb_zi = (float*)d_ws;         // 5000*256*4 = 5.12 MB scratch

  emb_gemm<<<dim3(VOCAB / 8), dim3(256), 0, stream>>>(emb, W1, b1, emb_zi);
  lstm_fused<<<dim3(NB / RPB), dim3(NTHR), 0, stream>>>(
      tokens, emb_zi, U1, W2, U2, b2, Wd, bd, out);
}

// Round 9
// 334.730 us; speedup vs baseline: 3.0910x; 1.1014x over previous
//
#include <hip/hip_runtime.h>

typedef float f4 __attribute__((ext_vector_type(4)));
typedef float f2 __attribute__((ext_vector_type(2)));

#define NB    1024
#define TT    256
#define EE    100
#define VOCAB 5000
#define GG1   256   // 4*H1
#define GG2   128   // 4*H2
#define RPB   2
#define NTHR  512

__device__ __forceinline__ float fast_sigmoid(float x) {
  return __builtin_amdgcn_rcpf(1.0f + __expf(-x));
}

// quad_perm DPP cross-lane (VALU pipe, no LDS): 0xB1 = xor1, 0x4E = xor2
template <int CTRL>
__device__ __forceinline__ float dppq(float x) {
  return __int_as_float(
      __builtin_amdgcn_mov_dpp(__float_as_int(x), CTRL, 0xF, 0xF, true));
}
__device__ __forceinline__ float swz_xor4(float x) {  // lane ^= 4 (LDS pipe)
  return __int_as_float(__builtin_amdgcn_ds_swizzle(__float_as_int(x), 0x101F));
}

// Reduce 4 gate-accumulators across a quad; lane sg (=lane&3) returns gate sg's sum.
__device__ __forceinline__ float qredsel(float ai, float af, float ag, float ao, int sg) {
  ai += dppq<0xB1>(ai); af += dppq<0xB1>(af);
  ag += dppq<0xB1>(ag); ao += dppq<0xB1>(ao);
  float pl = (sg & 1) ? af : ai;
  float ph = (sg & 1) ? ao : ag;
  pl += dppq<0x4E>(pl); ph += dppq<0x4E>(ph);
  return (sg & 2) ? ph : pl;
}

// Quad-cooperative activation + state update. z = pre-activation for gate sg.
// c authoritative on lane sg==1; h carried in-register on lane sg==3.
__device__ __forceinline__ void gate_up(float z, int sg, bool m, float& c, float& h) {
  const bool th = (sg == 2);
  float e = __expf(th ? 2.0f * z : -z);
  float r = __builtin_amdgcn_rcpf(1.0f + e);
  float v = th ? (1.0f - 2.0f * r) : r;            // lanes: i, f, g, o
  float ig = v * dppq<0x4E>(v);                    // lane0: i*g
  float fc = v * c;                                // lane1: f*c
  float cn = fc + dppq<0xB1>(ig);                  // lane1: c_new
  float cu = m ? cn : c;
  c = cu;
  float e2 = __expf(2.0f * cu);
  float tc = 1.0f - 2.0f * __builtin_amdgcn_rcpf(1.0f + e2);  // lane1: tanh(c)
  float hn = v * dppq<0x4E>(tc);                   // lane3: o*tanh(c)
  if (m) h = hn;
}

// ---- K1: emb_zi[v][u*4+g] = b1[g*64+u] + sum_k emb[v][k]*W1[k][g*64+u] ----
__global__ __launch_bounds__(256) void emb_gemm(
    const float* __restrict__ emb, const float* __restrict__ W1,
    const float* __restrict__ b1, float* __restrict__ emb_zi)
{
  __shared__ float sE[8][EE];
  const int j  = threadIdx.x;           // column g*64+u
  const int v0 = blockIdx.x * 8;
  for (int idx = j; idx < 8 * EE; idx += 256) {
    int r = idx / EE, k = idx % EE;
    sE[r][k] = emb[(size_t)(v0 + r) * EE + k];
  }
  __syncthreads();
  float acc[8];
  const float bb = b1[j];
  #pragma unroll
  for (int r = 0; r < 8; ++r) acc[r] = bb;
  for (int k = 0; k < EE; ++k) {
    float w = W1[k * GG1 + j];
    #pragma unroll
    for (int r = 0; r < 8; ++r) acc[r] = fmaf(sE[r][k], w, acc[r]);
  }
  const int slot = (j & 63) * 4 + (j >> 6);   // u*4 + g
  #pragma unroll
  for (int r = 0; r < 8; ++r) emb_zi[(size_t)(v0 + r) * GG1 + slot] = acc[r];
}

// ---- K2: persistent 2-layer LSTM; wave-specialized; 1 barrier/step ----
// Round-6 structure (RPB=2, 2 blocks/CU, 4 waves/SIMD), but the k-loop FMAs
// are packed along k into v_pk_fma_f32: weights stored as k-pair f2s
// {w[k],w[k+1]} per gate (natural layout, no broadcasts), h pairs fall out
// of ds_read_b128 as aligned register pairs.
// h-buffer sHC[parity][row][96]: floats 0..63 = h1, 64..95 = h2.
// Step i: writes -> parity i&1; reads <- parity (i&1)^1.
__global__ __launch_bounds__(NTHR) __attribute__((amdgpu_waves_per_eu(4, 4)))
void lstm_fused(
    const int* __restrict__ tokens, const float* __restrict__ emb_zi,
    const float* __restrict__ U1,
    const float* __restrict__ W2, const float* __restrict__ U2, const float* __restrict__ b2,
    const float* __restrict__ Wd, const float* __restrict__ bd,
    float* __restrict__ out)
{
  __shared__ __align__(16) float sHC[2][RPB][96];
  __shared__ int2 sTokP[TT];

  const int tid  = threadIdx.x;
  const int row0 = blockIdx.x * RPB;
  const bool L2g = (tid >= 256);
  const int  lt  = tid & 255;
  const int  u   = lt >> 2;            // L1 unit (0..63)
  const int  sg  = lt & 3;             // gate id within quad
  const int  u2  = lt >> 3;            // L2 unit (0..31)
  const int  s2  = lt & 7;             // L2 k-eighth

  // ---- weights into registers as k-pair f2s: wW[4*p+g] = {w[k0],w[k0+1]} ----
  // L1: p=0..7,  k0 = 16*sg + 2p, col g*64+u   (32 f2 = 64 floats)
  // L2: p=0..5,  k0 = 12*s2 + 2p, col g*32+u2  (24 f2 = 48 floats)
  f2 wW[32];
  float biasg = 0.0f;
  if (!L2g) {
    #pragma unroll
    for (int p = 0; p < 8; ++p) {
      int k0 = 16 * sg + 2 * p;
      #pragma unroll
      for (int g = 0; g < 4; ++g) {
        f2 w;
        w[0] = U1[(k0 + 0) * GG1 + g * 64 + u];
        w[1] = U1[(k0 + 1) * GG1 + g * 64 + u];
        wW[4 * p + g] = w;
      }
    }
  } else {
    #pragma unroll
    for (int p = 0; p < 6; ++p) {
      int k0 = 12 * s2 + 2 * p;        // pairs never straddle the W2/U2 boundary (64 even)
      const float* r0 = (k0 < 64) ? &W2[(size_t)k0 * GG2] : &U2[(size_t)(k0 - 64) * GG2];
      const float* r1 = (k0 + 1 < 64) ? &W2[(size_t)(k0 + 1) * GG2] : &U2[(size_t)(k0 + 1 - 64) * GG2];
      #pragma unroll
      for (int g = 0; g < 4; ++g) {
        f2 w;
        w[0] = r0[g * 32 + u2];
        w[1] = r1[g * 32 + u2];
        wW[4 * p + g] = w;
      }
    }
    biasg = b2[sg * 32 + u2];
  }
  asm volatile("" : "+v"(wW[0]), "+v"(wW[1]), "+v"(wW[2]), "+v"(wW[3]),
                    "+v"(wW[4]), "+v"(wW[5]), "+v"(wW[6]), "+v"(wW[7]),
                    "+v"(wW[8]), "+v"(wW[9]), "+v"(wW[10]), "+v"(wW[11]),
                    "+v"(wW[12]), "+v"(wW[13]), "+v"(wW[14]), "+v"(wW[15]));
  asm volatile("" : "+v"(wW[16]), "+v"(wW[17]), "+v"(wW[18]), "+v"(wW[19]),
                    "+v"(wW[20]), "+v"(wW[21]), "+v"(wW[22]), "+v"(wW[23]),
                    "+v"(wW[24]), "+v"(wW[25]), "+v"(wW[26]), "+v"(wW[27]),
                    "+v"(wW[28]), "+v"(wW[29]), "+v"(wW[30]), "+v"(wW[31]));

  // ---- one-time LDS init ----
  if (tid < TT)
    sTokP[tid] = make_int2(tokens[(size_t)row0 * TT + tid],
                           tokens[(size_t)(row0 + 1) * TT + tid]);
  if (tid < 2 * RPB * 96) ((float*)sHC)[tid] = 0.0f;
  float c0 = 0.0f, c1 = 0.0f;          // cell state per row (lane sg==1)
  float h0r = 0.0f, h1r = 0.0f;        // hidden per row (writer lane)
  __syncthreads();

  // ---- prologue (L1 lanes): token pair + z_x for t=0 ----
  int2  tokc = make_int2(0, 0);
  float zxc0 = 0.f, zxc1 = 0.f;
  if (!L2g) {
    tokc = sTokP[0];
    zxc0 = emb_zi[(size_t)tokc.x * GG1 + lt];
    zxc1 = emb_zi[(size_t)tokc.y * GG1 + lt];
  }

  for (int i = 0; i <= TT; ++i) {
    const int rbuf = (i & 1) ^ 1, wbuf = i & 1;
    if (!L2g) {
      if (i < TT) {                                 // L1 step t = i
        const bool m0 = (tokc.x != 0), m1 = (tokc.y != 0);
        int2 tokn = make_int2(0, 0);
        float zxn0 = 0.f, zxn1 = 0.f;
        if (i + 1 < TT) {                           // prefetch z_x(t+1)
          tokn = sTokP[i + 1];
          zxn0 = emb_zi[(size_t)tokn.x * GG1 + lt];
          zxn1 = emb_zi[(size_t)tokn.y * GG1 + lt];
        }
        f2 a0[4] = {{0.f,0.f},{0.f,0.f},{0.f,0.f},{0.f,0.f}};
        f2 a1[4] = {{0.f,0.f},{0.f,0.f},{0.f,0.f},{0.f,0.f}};
        #pragma unroll
        for (int q = 0; q < 4; ++q) {               // k = 16sg+4q .. +3
          f4 h0 = *(const f4*)&sHC[rbuf][0][16 * sg + 4 * q];
          f4 h1 = *(const f4*)&sHC[rbuf][1][16 * sg + 4 * q];
          f2 h0lo = __builtin_shufflevector(h0, h0, 0, 1);
          f2 h0hi = __builtin_shufflevector(h0, h0, 2, 3);
          f2 h1lo = __builtin_shufflevector(h1, h1, 0, 1);
          f2 h1hi = __builtin_shufflevector(h1, h1, 2, 3);
          #pragma unroll
          for (int g = 0; g < 4; ++g) {
            a0[g] = __builtin_elementwise_fma(h0lo, wW[8 * q + g], a0[g]);
            a0[g] = __builtin_elementwise_fma(h0hi, wW[8 * q + 4 + g], a0[g]);
            a1[g] = __builtin_elementwise_fma(h1lo, wW[8 * q + g], a1[g]);
            a1[g] = __builtin_elementwise_fma(h1hi, wW[8 * q + 4 + g], a1[g]);
          }
        }
        float z0 = qredsel(a0[0][0] + a0[0][1], a0[1][0] + a0[1][1],
                           a0[2][0] + a0[2][1], a0[3][0] + a0[3][1], sg) + zxc0;
        float z1 = qredsel(a1[0][0] + a1[0][1], a1[1][0] + a1[1][1],
                           a1[2][0] + a1[2][1], a1[3][0] + a1[3][1], sg) + zxc1;
        gate_up(z0, sg, m0, c0, h0r);
        gate_up(z1, sg, m1, c1, h1r);
        if (sg == 3) { sHC[wbuf][0][u] = h0r; sHC[wbuf][1][u] = h1r; }
        tokc = tokn; zxc0 = zxn0; zxc1 = zxn1;
      }
    } else {
      if (i >= 1) {                                 // L2 step tt = i-1
        const int tt = i - 1;
        int2 tk = sTokP[tt];
        const bool m0 = (tk.x != 0), m1 = (tk.y != 0);
        f2 a0[4] = {{0.f,0.f},{0.f,0.f},{0.f,0.f},{0.f,0.f}};
        f2 a1[4] = {{0.f,0.f},{0.f,0.f},{0.f,0.f},{0.f,0.f}};
        #pragma unroll
        for (int q = 0; q < 3; ++q) {               // k = 12s2+4q .. +3
          f4 h0 = *(const f4*)&sHC[rbuf][0][12 * s2 + 4 * q];
          f4 h1 = *(const f4*)&sHC[rbuf][1][12 * s2 + 4 * q];
          f2 h0lo = __builtin_shufflevector(h0, h0, 0, 1);
          f2 h0hi = __builtin_shufflevector(h0, h0, 2, 3);
          f2 h1lo = __builtin_shufflevector(h1, h1, 0, 1);
          f2 h1hi = __builtin_shufflevector(h1, h1, 2, 3);
          #pragma unroll
          for (int g = 0; g < 4; ++g) {
            a0[g] = __builtin_elementwise_fma(h0lo, wW[8 * q + g], a0[g]);
            a0[g] = __builtin_elementwise_fma(h0hi, wW[8 * q + 4 + g], a0[g]);
            a1[g] = __builtin_elementwise_fma(h1lo, wW[8 * q + g], a1[g]);
            a1[g] = __builtin_elementwise_fma(h1hi, wW[8 * q + 4 + g], a1[g]);
          }
        }
        float q0 = qredsel(a0[0][0] + a0[0][1], a0[1][0] + a0[1][1],
                           a0[2][0] + a0[2][1], a0[3][0] + a0[3][1], sg);
        float q1 = qredsel(a1[0][0] + a1[0][1], a1[1][0] + a1[1][1],
                           a1[2][0] + a1[2][1], a1[3][0] + a1[3][1], sg);
        float z0 = q0 + swz_xor4(q0) + biasg;       // full 8-lane k-sum
        float z1 = q1 + swz_xor4(q1) + biasg;
        gate_up(z0, sg, m0, c0, h0r);
        gate_up(z1, sg, m1, c1, h1r);
        if (s2 == 3) { sHC[wbuf][0][64 + u2] = h0r; sHC[wbuf][1][64 + u2] = h1r; }
      }
    }
    __syncthreads();
  }

  // ---- epilogue: out = sigmoid(h2 @ Wd + bd); final h2 in parity TT&1 = 0 ----
  if (tid < RPB * 4) {
    int r = tid >> 2, o = tid & 3;
    float a = bd[o];
    #pragma unroll
    for (int kk = 0; kk < 32; ++kk)
      a = fmaf(sHC[0][r][64 + kk], Wd[kk * 4 + o], a);
    out[(size_t)(row0 + r) * 4 + o] = fast_sigmoid(a);
  }
}

extern "C" void kernel_launch(void* const* d_in, const int* in_sizes, int n_in,
                              void* d_out, int out_size, void* d_ws, size_t ws_size,
                              hipStream_t stream) {
  const int*   tokens = (const int*)d_in[0];
  const float* emb    = (const float*)d_in[1];
  const float* W1     = (const float*)d_in[2];
  const float* U1     = (const float*)d_in[3];
  const float* b1     = (const float*)d_in[4];
  const float* W2     = (const float*)d_in[5];
  const float* U2     = (const float*)d_in[6];
  const float* b2     = (const float*)d_in[7];
  const float* Wd     = (const float*)d_in[8];
  const float* bd     = (const float*)d_in[9];
  float* out    = (float*)d_out;
  float* emb_zi = (float*)d_ws;         // 5000*256*4 = 5.12 MB scratch

  emb_gemm<<<dim3(VOCAB / 8), dim3(256), 0, stream>>>(emb, W1, b1, emb_zi);
  lstm_fused<<<dim3(NB / RPB), dim3(NTHR), 0, stream>>>(
      tokens, emb_zi, U1, W2, U2, b2, Wd, bd, out);
}

// Round 10
// 329.779 us; speedup vs baseline: 3.1374x; 1.0150x over previous
//
#include <hip/hip_runtime.h>

typedef float f4 __attribute__((ext_vector_type(4)));
typedef _Float16 hp2 __attribute__((ext_vector_type(2)));

#define NB    1024
#define TT    256
#define EE    100
#define VOCAB 5000
#define GG1   256   // 4*H1
#define GG2   128   // 4*H2
#define RPB   2
#define NTHR  512

__device__ __forceinline__ float fast_sigmoid(float x) {
  return __builtin_amdgcn_rcpf(1.0f + __expf(-x));
}

// quad_perm DPP cross-lane (VALU pipe, no LDS): 0xB1 = xor1, 0x4E = xor2
template <int CTRL>
__device__ __forceinline__ float dppq(float x) {
  return __int_as_float(
      __builtin_amdgcn_mov_dpp(__float_as_int(x), CTRL, 0xF, 0xF, true));
}
__device__ __forceinline__ float swz_xor4(float x) {  // lane ^= 4 (LDS pipe)
  return __int_as_float(__builtin_amdgcn_ds_swizzle(__float_as_int(x), 0x101F));
}

// Reduce 4 gate-accumulators across a quad; lane sg (=lane&3) returns gate sg's sum.
__device__ __forceinline__ float qredsel(float ai, float af, float ag, float ao, int sg) {
  ai += dppq<0xB1>(ai); af += dppq<0xB1>(af);
  ag += dppq<0xB1>(ag); ao += dppq<0xB1>(ao);
  float pl = (sg & 1) ? af : ai;
  float ph = (sg & 1) ? ao : ag;
  pl += dppq<0x4E>(pl); ph += dppq<0x4E>(ph);
  return (sg & 2) ? ph : pl;
}

// Quad-cooperative activation + state update. z = pre-activation for gate sg.
// c authoritative on lane sg==1; h carried in-register on lane sg==3.
__device__ __forceinline__ void gate_up(float z, int sg, bool m, float& c, float& h) {
  const bool th = (sg == 2);
  float e = __expf(th ? 2.0f * z : -z);
  float r = __builtin_amdgcn_rcpf(1.0f + e);
  float v = th ? (1.0f - 2.0f * r) : r;            // lanes: i, f, g, o
  float ig = v * dppq<0x4E>(v);                    // lane0: i*g
  float fc = v * c;                                // lane1: f*c
  float cn = fc + dppq<0xB1>(ig);                  // lane1: c_new
  float cu = m ? cn : c;
  c = cu;
  float e2 = __expf(2.0f * cu);
  float tc = 1.0f - 2.0f * __builtin_amdgcn_rcpf(1.0f + e2);  // lane1: tanh(c)
  float hn = v * dppq<0x4E>(tc);                   // lane3: o*tanh(c)
  if (m) h = hn;
}

// ---- K1: emb_zi[v][u*4+g] = b1[g*64+u] + sum_k emb[v][k]*W1[k][g*64+u] ----
__global__ __launch_bounds__(256) void emb_gemm(
    const float* __restrict__ emb, const float* __restrict__ W1,
    const float* __restrict__ b1, float* __restrict__ emb_zi)
{
  __shared__ float sE[8][EE];
  const int j  = threadIdx.x;           // column g*64+u
  const int v0 = blockIdx.x * 8;
  for (int idx = j; idx < 8 * EE; idx += 256) {
    int r = idx / EE, k = idx % EE;
    sE[r][k] = emb[(size_t)(v0 + r) * EE + k];
  }
  __syncthreads();
  float acc[8];
  const float bb = b1[j];
  #pragma unroll
  for (int r = 0; r < 8; ++r) acc[r] = bb;
  for (int k = 0; k < EE; ++k) {
    float w = W1[k * GG1 + j];
    #pragma unroll
    for (int r = 0; r < 8; ++r) acc[r] = fmaf(sE[r][k], w, acc[r]);
  }
  const int slot = (j & 63) * 4 + (j >> 6);   // u*4 + g
  #pragma unroll
  for (int r = 0; r < 8; ++r) emb_zi[(size_t)(v0 + r) * GG1 + slot] = acc[r];
}

// ---- K2: persistent 2-layer LSTM; wave-specialized; 1 barrier/step ----
// Round-6 structure (RPB=2, 2 blocks/CU, 4 waves/SIMD); the k-loop uses
// v_dot2_f32_f16 (__builtin_amdgcn_fdot2): weights as f16 k-pair half2s,
// h stored in LDS as f16 (halves ds bytes), f32 accumulate (exact).
// h-buffer sHC[parity][row][96] (f16): 0..63 = h1, 64..95 = h2.
// Step i: writes -> parity i&1; reads <- parity (i&1)^1.
__global__ __launch_bounds__(NTHR) __attribute__((amdgpu_waves_per_eu(4, 4)))
void lstm_fused(
    const int* __restrict__ tokens, const float* __restrict__ emb_zi,
    const float* __restrict__ U1,
    const float* __restrict__ W2, const float* __restrict__ U2, const float* __restrict__ b2,
    const float* __restrict__ Wd, const float* __restrict__ bd,
    float* __restrict__ out)
{
  __shared__ __align__(16) _Float16 sHC[2][RPB][96];
  __shared__ int2 sTokP[TT];

  const int tid  = threadIdx.x;
  const int row0 = blockIdx.x * RPB;
  const bool L2g = (tid >= 256);
  const int  lt  = tid & 255;
  const int  u   = lt >> 2;            // L1 unit (0..63)
  const int  sg  = lt & 3;             // gate id within quad
  const int  u2  = lt >> 3;            // L2 unit (0..31)
  const int  s2  = lt & 7;             // L2 k-eighth

  // ---- weights into registers as f16 k-pair half2s: wH[4*p+g] = {w[k0],w[k0+1]} ----
  // L1: p=0..7,  k0 = 16*sg + 2p, col g*64+u   (32 half2 regs)
  // L2: p=0..5,  k0 = 12*s2 + 2p, col g*32+u2  (24 half2 regs)
  hp2 wH[32];
  float biasg = 0.0f;
  if (!L2g) {
    #pragma unroll
    for (int p = 0; p < 8; ++p) {
      int k0 = 16 * sg + 2 * p;
      #pragma unroll
      for (int g = 0; g < 4; ++g) {
        hp2 w;
        w[0] = (_Float16)U1[(k0 + 0) * GG1 + g * 64 + u];
        w[1] = (_Float16)U1[(k0 + 1) * GG1 + g * 64 + u];
        wH[4 * p + g] = w;
      }
    }
  } else {
    #pragma unroll
    for (int p = 0; p < 6; ++p) {
      int k0 = 12 * s2 + 2 * p;        // even -> never straddles the W2/U2 boundary
      const float* r0 = (k0 < 64) ? &W2[(size_t)k0 * GG2] : &U2[(size_t)(k0 - 64) * GG2];
      const float* r1 = (k0 + 1 < 64) ? &W2[(size_t)(k0 + 1) * GG2] : &U2[(size_t)(k0 + 1 - 64) * GG2];
      #pragma unroll
      for (int g = 0; g < 4; ++g) {
        hp2 w;
        w[0] = (_Float16)r0[g * 32 + u2];
        w[1] = (_Float16)r1[g * 32 + u2];
        wH[4 * p + g] = w;
      }
    }
    biasg = b2[sg * 32 + u2];
  }

  // ---- one-time LDS init ----
  if (tid < TT)
    sTokP[tid] = make_int2(tokens[(size_t)row0 * TT + tid],
                           tokens[(size_t)(row0 + 1) * TT + tid]);
  if (tid < 2 * RPB * 96) ((_Float16*)sHC)[tid] = (_Float16)0.0f;
  float c0 = 0.0f, c1 = 0.0f;          // cell state per row (lane sg==1)
  float h0r = 0.0f, h1r = 0.0f;        // hidden per row (writer lane)
  __syncthreads();

  // ---- prologue (L1 lanes): token pair + z_x for t=0 ----
  int2  tokc = make_int2(0, 0);
  float zxc0 = 0.f, zxc1 = 0.f;
  if (!L2g) {
    tokc = sTokP[0];
    zxc0 = emb_zi[(size_t)tokc.x * GG1 + lt];
    zxc1 = emb_zi[(size_t)tokc.y * GG1 + lt];
  }

  for (int i = 0; i <= TT; ++i) {
    const int rbuf = (i & 1) ^ 1, wbuf = i & 1;
    if (!L2g) {
      if (i < TT) {                                 // L1 step t = i
        const bool m0 = (tokc.x != 0), m1 = (tokc.y != 0);
        int2 tokn = make_int2(0, 0);
        float zxn0 = 0.f, zxn1 = 0.f;
        if (i + 1 < TT) {                           // prefetch z_x(t+1)
          tokn = sTokP[i + 1];
          zxn0 = emb_zi[(size_t)tokn.x * GG1 + lt];
          zxn1 = emb_zi[(size_t)tokn.y * GG1 + lt];
        }
        // h halfs [16sg, 16sg+16) for each row: 2x 16B reads per row
        int4 hA0 = *(const int4*)&sHC[rbuf][0][16 * sg];
        int4 hA1 = *(const int4*)&sHC[rbuf][0][16 * sg + 8];
        int4 hB0 = *(const int4*)&sHC[rbuf][1][16 * sg];
        int4 hB1 = *(const int4*)&sHC[rbuf][1][16 * sg + 8];
        const hp2* hp0a = (const hp2*)&hA0;  // 4 half2 (k-pairs 0..3)
        const hp2* hp0b = (const hp2*)&hA1;  // 4 half2 (k-pairs 4..7)
        const hp2* hp1a = (const hp2*)&hB0;
        const hp2* hp1b = (const hp2*)&hB1;
        float a0[4] = {0.f, 0.f, 0.f, 0.f};
        float a1[4] = {0.f, 0.f, 0.f, 0.f};
        #pragma unroll
        for (int p = 0; p < 4; ++p) {
          #pragma unroll
          for (int g = 0; g < 4; ++g) {
            a0[g] = __builtin_amdgcn_fdot2(hp0a[p], wH[4 * p + g], a0[g], false);
            a1[g] = __builtin_amdgcn_fdot2(hp1a[p], wH[4 * p + g], a1[g], false);
            a0[g] = __builtin_amdgcn_fdot2(hp0b[p], wH[4 * (p + 4) + g], a0[g], false);
            a1[g] = __builtin_amdgcn_fdot2(hp1b[p], wH[4 * (p + 4) + g], a1[g], false);
          }
        }
        float z0 = qredsel(a0[0], a0[1], a0[2], a0[3], sg) + zxc0;
        float z1 = qredsel(a1[0], a1[1], a1[2], a1[3], sg) + zxc1;
        gate_up(z0, sg, m0, c0, h0r);
        gate_up(z1, sg, m1, c1, h1r);
        if (sg == 3) {
          sHC[wbuf][0][u] = (_Float16)h0r;
          sHC[wbuf][1][u] = (_Float16)h1r;
        }
        tokc = tokn; zxc0 = zxn0; zxc1 = zxn1;
      }
    } else {
      if (i >= 1) {                                 // L2 step tt = i-1
        const int tt = i - 1;
        int2 tk = sTokP[tt];
        const bool m0 = (tk.x != 0), m1 = (tk.y != 0);
        // h halfs [12s2, 12s2+12): 3x 8B reads per row (8-aligned)
        int2 hA0 = *(const int2*)&sHC[rbuf][0][12 * s2];
        int2 hA1 = *(const int2*)&sHC[rbuf][0][12 * s2 + 4];
        int2 hA2 = *(const int2*)&sHC[rbuf][0][12 * s2 + 8];
        int2 hB0 = *(const int2*)&sHC[rbuf][1][12 * s2];
        int2 hB1 = *(const int2*)&sHC[rbuf][1][12 * s2 + 4];
        int2 hB2 = *(const int2*)&sHC[rbuf][1][12 * s2 + 8];
        hp2 hp0[6], hp1[6];
        hp0[0] = ((const hp2*)&hA0)[0]; hp0[1] = ((const hp2*)&hA0)[1];
        hp0[2] = ((const hp2*)&hA1)[0]; hp0[3] = ((const hp2*)&hA1)[1];
        hp0[4] = ((const hp2*)&hA2)[0]; hp0[5] = ((const hp2*)&hA2)[1];
        hp1[0] = ((const hp2*)&hB0)[0]; hp1[1] = ((const hp2*)&hB0)[1];
        hp1[2] = ((const hp2*)&hB1)[0]; hp1[3] = ((const hp2*)&hB1)[1];
        hp1[4] = ((const hp2*)&hB2)[0]; hp1[5] = ((const hp2*)&hB2)[1];
        float a0[4] = {0.f, 0.f, 0.f, 0.f};
        float a1[4] = {0.f, 0.f, 0.f, 0.f};
        #pragma unroll
        for (int p = 0; p < 6; ++p) {
          #pragma unroll
          for (int g = 0; g < 4; ++g) {
            a0[g] = __builtin_amdgcn_fdot2(hp0[p], wH[4 * p + g], a0[g], false);
            a1[g] = __builtin_amdgcn_fdot2(hp1[p], wH[4 * p + g], a1[g], false);
          }
        }
        float q0 = qredsel(a0[0], a0[1], a0[2], a0[3], sg);
        float q1 = qredsel(a1[0], a1[1], a1[2], a1[3], sg);
        float z0 = q0 + swz_xor4(q0) + biasg;       // full 8-lane k-sum
        float z1 = q1 + swz_xor4(q1) + biasg;
        gate_up(z0, sg, m0, c0, h0r);
        gate_up(z1, sg, m1, c1, h1r);
        if (s2 == 3) {
          sHC[wbuf][0][64 + u2] = (_Float16)h0r;
          sHC[wbuf][1][64 + u2] = (_Float16)h1r;
        }
      }
    }
    __syncthreads();
  }

  // ---- epilogue: out = sigmoid(h2 @ Wd + bd); final h2 in parity TT&1 = 0 ----
  if (tid < RPB * 4) {
    int r = tid >> 2, o = tid & 3;
    float a = bd[o];
    #pragma unroll
    for (int kk = 0; kk < 32; ++kk)
      a = fmaf((float)sHC[0][r][64 + kk], Wd[kk * 4 + o], a);
    out[(size_t)(row0 + r) * 4 + o] = fast_sigmoid(a);
  }
}

extern "C" void kernel_launch(void* const* d_in, const int* in_sizes, int n_in,
                              void* d_out, int out_size, void* d_ws, size_t ws_size,
                              hipStream_t stream) {
  const int*   tokens = (const int*)d_in[0];
  const float* emb    = (const float*)d_in[1];
  const float* W1     = (const float*)d_in[2];
  const float* U1     = (const float*)d_in[3];
  const float* b1     = (const float*)d_in[4];
  const float* W2     = (const float*)d_in[5];
  const float* U2     = (const float*)d_in[6];
  const float* b2     = (const float*)d_in[7];
  const float* Wd     = (const float*)d_in[8];
  const float* bd     = (const float*)d_in[9];
  float* out    = (float*)d_out;
  float* emb_zi = (float*)d_ws;         // 5000*256*4 = 5.12 MB scratch

  emb_gemm<<<dim3(VOCAB / 8), dim3(256), 0, stream>>>(emb, W1, b1, emb_zi);
  lstm_fused<<<dim3(NB / RPB), dim3(NTHR), 0, stream>>>(
      tokens, emb_zi, U1, W2, U2, b2, Wd, bd, out);
}

// Round 11
// 241.608 us; speedup vs baseline: 4.2823x; 1.3649x over previous
//
#include <hip/hip_runtime.h>

typedef _Float16 hp2 __attribute__((ext_vector_type(2)));

#define NB    1024
#define TT    256
#define EE    100
#define VOCAB 5000
#define GG1   256   // 4*H1
#define GG2   128   // 4*H2

__device__ __forceinline__ float fast_sigmoid(float x) {
  return __builtin_amdgcn_rcpf(1.0f + __expf(-x));
}
__device__ __forceinline__ float fast_tanh(float x) {
  return 1.0f - 2.0f * __builtin_amdgcn_rcpf(1.0f + __expf(2.0f * x));
}

// ---- K1: emb_zi[v][u*4+g] = b1[g*64+u] + sum_k emb[v][k]*W1[k][g*64+u] ----
// Interleaved so L1 lane u grabs its 4 gate pre-activations as one float4.
__global__ __launch_bounds__(256) void emb_gemm(
    const float* __restrict__ emb, const float* __restrict__ W1,
    const float* __restrict__ b1, float* __restrict__ emb_zi)
{
  __shared__ float sE[8][EE];
  const int j  = threadIdx.x;           // column g*64+u
  const int v0 = blockIdx.x * 8;
  for (int idx = j; idx < 8 * EE; idx += 256) {
    int r = idx / EE, k = idx % EE;
    sE[r][k] = emb[(size_t)(v0 + r) * EE + k];
  }
  __syncthreads();
  float acc[8];
  const float bb = b1[j];
  #pragma unroll
  for (int r = 0; r < 8; ++r) acc[r] = bb;
  for (int k = 0; k < EE; ++k) {
    float w = W1[k * GG1 + j];
    #pragma unroll
    for (int r = 0; r < 8; ++r) acc[r] = fmaf(sE[r][k], w, acc[r]);
  }
  const int slot = (j & 63) * 4 + (j >> 6);   // u*4 + g
  #pragma unroll
  for (int r = 0; r < 8; ++r) emb_zi[(size_t)(v0 + r) * GG1 + slot] = acc[r];
}

// ---- K2: one wave = one batch row, both layers, zero cross-wave sync ----
// Lane u: L1 unit u complete (64 k x 4 gates, fdot2, per-lane activations).
// L2: unit u2 = u&31, k-half s = u>>5 (48 k each), one shfl_xor(32) reduce.
// h1|h2 handoff through a 192B f16 LDS buffer; single-wave block so LDS
// ordering needs only waitcnt (__syncthreads on 1 wave is ~free).
// waves_per_eu(1,1): 1 wave/SIMD, 512-reg budget -> all 224 weight half2s
// in registers.
__global__ __launch_bounds__(64) __attribute__((amdgpu_waves_per_eu(1, 1)))
void lstm_row(
    const int* __restrict__ tokens, const float* __restrict__ emb_zi,
    const float* __restrict__ U1,
    const float* __restrict__ W2, const float* __restrict__ U2, const float* __restrict__ b2,
    const float* __restrict__ Wd, const float* __restrict__ bd,
    float* __restrict__ out)
{
  __shared__ __align__(16) _Float16 sH[96];   // 0..63 = h1(f16), 64..95 = h2(f16)
  __shared__ int sTok[TT];

  const int u   = threadIdx.x;        // 0..63
  const int row = blockIdx.x;
  const int u2  = u & 31;             // L2 unit
  const int s   = u >> 5;             // L2 k-half

  // ---- L1 weights: wA[4p+g] = {U1[2p][g*64+u], U1[2p+1][g*64+u]}, p=0..31 ----
  hp2 wA[128];
  #pragma unroll
  for (int p = 0; p < 32; ++p) {
    #pragma unroll
    for (int g = 0; g < 4; ++g) {
      hp2 w;
      w[0] = (_Float16)U1[(2 * p + 0) * GG1 + g * 64 + u];
      w[1] = (_Float16)U1[(2 * p + 1) * GG1 + g * 64 + u];
      wA[4 * p + g] = w;
    }
  }
  // ---- L2 weights: k in [48s, 48s+48), pairs p=0..23; rows<64 -> W2, else U2 ----
  hp2 wB[96];
  #pragma unroll
  for (int p = 0; p < 24; ++p) {
    int k0 = 48 * s + 2 * p;          // even: never straddles the 64 boundary
    const float* r0 = (k0     < 64) ? &W2[(size_t)k0 * GG2]       : &U2[(size_t)(k0 - 64) * GG2];
    const float* r1 = (k0 + 1 < 64) ? &W2[(size_t)(k0 + 1) * GG2] : &U2[(size_t)(k0 + 1 - 64) * GG2];
    #pragma unroll
    for (int g = 0; g < 4; ++g) {
      hp2 w;
      w[0] = (_Float16)r0[g * 32 + u2];
      w[1] = (_Float16)r1[g * 32 + u2];
      wB[4 * p + g] = w;
    }
  }
  const float bi2 = b2[u2], bf2 = b2[32 + u2], bg2 = b2[64 + u2], bo2 = b2[96 + u2];

  // ---- init ----
  ((int4*)sTok)[u] = ((const int4*)(tokens + (size_t)row * TT))[u];
  sH[u] = (_Float16)0.0f;
  if (u < 32) sH[64 + u] = (_Float16)0.0f;
  __syncthreads();

  float c1 = 0.f, h1 = 0.f, c2 = 0.f, h2v = 0.f;
  int tok_cur = sTok[0];
  float4 zx = *(const float4*)&emb_zi[(size_t)tok_cur * GG1 + 4 * u];

  for (int t = 0; t < TT; ++t) {
    const bool m = (tok_cur != 0);
    int tok_next = (t + 1 < TT) ? sTok[t + 1] : 0;

    // ---- phase A: L1 unit u (full 64-k dot, 4 gates) ----
    float a0 = zx.x, a1 = zx.y, a2 = zx.z, a3 = zx.w;
    #pragma unroll
    for (int q = 0; q < 8; ++q) {               // h1(t-1): 8 x b128 uniform reads
      int4 hq = ((const int4*)sH)[q];
      #pragma unroll
      for (int pp = 0; pp < 4; ++pp) {
        hp2 hv = ((const hp2*)&hq)[pp];
        const int p = 4 * q + pp;
        a0 = __builtin_amdgcn_fdot2(hv, wA[4 * p + 0], a0, false);
        a1 = __builtin_amdgcn_fdot2(hv, wA[4 * p + 1], a1, false);
        a2 = __builtin_amdgcn_fdot2(hv, wA[4 * p + 2], a2, false);
        a3 = __builtin_amdgcn_fdot2(hv, wA[4 * p + 3], a3, false);
      }
    }
    // issue next-step z_x prefetch now; consumed at loop end (covers phase B)
    float4 zxn = zx;
    if (t + 1 < TT) zxn = *(const float4*)&emb_zi[(size_t)tok_next * GG1 + 4 * u];

    {
      float iv = fast_sigmoid(a0);
      float fv = fast_sigmoid(a1);
      float gv = fast_tanh(a2);
      float ov = fast_sigmoid(a3);
      if (m) { c1 = fv * c1 + iv * gv; h1 = ov * fast_tanh(c1); }
    }
    sH[u] = (_Float16)h1;
    __syncthreads();

    // ---- phase B: L2 unit u2, k-half s ----
    float b0 = 0.f, b1v = 0.f, b2v = 0.f, b3 = 0.f;
    #pragma unroll
    for (int q = 0; q < 6; ++q) {               // halfs [48s, 48s+48): 6 x b128
      int4 hq = ((const int4*)sH)[6 * s + q];
      #pragma unroll
      for (int pp = 0; pp < 4; ++pp) {
        hp2 hv = ((const hp2*)&hq)[pp];
        const int p = 4 * q + pp;
        b0  = __builtin_amdgcn_fdot2(hv, wB[4 * p + 0], b0,  false);
        b1v = __builtin_amdgcn_fdot2(hv, wB[4 * p + 1], b1v, false);
        b2v = __builtin_amdgcn_fdot2(hv, wB[4 * p + 2], b2v, false);
        b3  = __builtin_amdgcn_fdot2(hv, wB[4 * p + 3], b3,  false);
      }
    }
    b0  += __shfl_xor(b0, 32);
    b1v += __shfl_xor(b1v, 32);
    b2v += __shfl_xor(b2v, 32);
    b3  += __shfl_xor(b3, 32);
    {
      float i2 = fast_sigmoid(b0 + bi2);
      float f2 = fast_sigmoid(b1v + bf2);
      float g2 = fast_tanh(b2v + bg2);
      float o2 = fast_sigmoid(b3 + bo2);
      if (m) { c2 = f2 * c2 + i2 * g2; h2v = o2 * fast_tanh(c2); }
    }
    if (s == 0) sH[64 + u2] = (_Float16)h2v;
    __syncthreads();

    tok_cur = tok_next;
    zx = zxn;
  }

  // ---- epilogue: out = sigmoid(h2 @ Wd + bd) ----
  if (u < 4) {
    float a = bd[u];
    #pragma unroll
    for (int k = 0; k < 32; ++k)
      a = fmaf((float)sH[64 + k], Wd[k * 4 + u], a);
    out[(size_t)row * 4 + u] = fast_sigmoid(a);
  }
}

extern "C" void kernel_launch(void* const* d_in, const int* in_sizes, int n_in,
                              void* d_out, int out_size, void* d_ws, size_t ws_size,
                              hipStream_t stream) {
  const int*   tokens = (const int*)d_in[0];
  const float* emb    = (const float*)d_in[1];
  const float* W1     = (const float*)d_in[2];
  const float* U1     = (const float*)d_in[3];
  const float* b1     = (const float*)d_in[4];
  const float* W2     = (const float*)d_in[5];
  const float* U2     = (const float*)d_in[6];
  const float* b2     = (const float*)d_in[7];
  const float* Wd     = (const float*)d_in[8];
  const float* bd     = (const float*)d_in[9];
  float* out    = (float*)d_out;
  float* emb_zi = (float*)d_ws;         // 5000*256*4 = 5.12 MB scratch

  emb_gemm<<<dim3(VOCAB / 8), dim3(256), 0, stream>>>(emb, W1, b1, emb_zi);
  lstm_row<<<dim3(NB), dim3(64), 0, stream>>>(
      tokens, emb_zi, U1, W2, U2, b2, Wd, bd, out);
}